// Round 1
// baseline (680.552 us; speedup 1.0000x reference)
//
#include <hip/hip_runtime.h>
#include <stdint.h>

#define C_ 1024
#define K_ 16
#define S_ 32
#define Y_ 128
#define N_ (C_ * K_)          // 16384 cells
#define ACT_THR 10
#define PERM_THR 0.5f
#define POT 0.1f              // LR * MOD
#define PUN 0.01f             // POT * 0.1

// ---- workspace layout (u32 indices) ----
#define WS_NUM_ACTIVE 0
#define WS_NUM_PRED   1
#define WS_NBURST     2
#define WS_LEARN_CNT  3
#define WS_PREV_ANY   4
#define WS_BURSTMASK  8        // 32 words  (1024 column bits)
#define WS_PREVMASK   64       // 512 words (16384 cell bits)
#define WS_CELLINFO   1024     // N words: pred(1b) | best_seg<<8 | best_overlap<<16
#define WS_LIST       (1024 + N_) // up to N winner-cell ids
#define WS_CONBITS    65536    // word offset (256KB): N*64 u64 = 8 MB connected-bit table

// conbits layout: u64 per (cell, lane). Bit 4*i+e of conbits[cell*64+lane] =
// connected bit for synapse (lane&31)*4+e of segment 2*i+(lane>>5) of cell.
// This matches exactly the per-lane access pattern of phase1/phase2 below.

// ---------------------------------------------------------------------------
// Kernel 1: pack prev_active bits into ws bitmask, zero counters, prev_any.
// ---------------------------------------------------------------------------
__global__ __launch_bounds__(512) void pack_kernel(const int* __restrict__ prev,
                                                   unsigned* __restrict__ ws) {
    const int tid = threadIdx.x;
    if (tid < 64) ws[tid] = 0u;   // counters + burst mask
    __syncthreads();
    const int4* p = reinterpret_cast<const int4*>(prev + tid * 32);
    unsigned m = 0u;
    #pragma unroll
    for (int q = 0; q < 8; ++q) {
        const int4 v = p[q];
        m |= (v.x != 0 ? 1u : 0u) << (q * 4 + 0);
        m |= (v.y != 0 ? 1u : 0u) << (q * 4 + 1);
        m |= (v.z != 0 ? 1u : 0u) << (q * 4 + 2);
        m |= (v.w != 0 ? 1u : 0u) << (q * 4 + 3);
    }
    ws[WS_PREVMASK + tid] = m;
    const bool any = (__ballot(m != 0u) != 0ull);
    if ((tid & 63) == 0 && any) atomicOr(&ws[WS_PREV_ANY], 1u);
}

// ---------------------------------------------------------------------------
// Kernel 2: connected-bit precompute. Pure stream: vol+cons (536MB) -> 8MB
// nibble table. One wave per cell, 16 iters of float4+float4, one 8B store.
// ---------------------------------------------------------------------------
__global__ __launch_bounds__(256) void precompute_kernel(const float* __restrict__ vol,
                                                         const float* __restrict__ cons,
                                                         unsigned long long* __restrict__ conbits) {
    const int tid  = threadIdx.x;
    const int wave = tid >> 6;
    const int lane = tid & 63;
    const int half = lane >> 5;
    const int l32  = lane & 31;
    const int cell = blockIdx.x * 4 + wave;
    const size_t base = (size_t)cell * (S_ * Y_) + (size_t)half * Y_ + (size_t)(l32 * 4);

    // 2-deep rotating prefetch (addresses stride 256 floats = 2 segments/iter)
    float4 v0 = *reinterpret_cast<const float4*>(vol  + base);
    float4 s0 = *reinterpret_cast<const float4*>(cons + base);
    float4 v1 = *reinterpret_cast<const float4*>(vol  + base + 256);
    float4 s1 = *reinterpret_cast<const float4*>(cons + base + 256);

    unsigned long long bits = 0ull;
    #pragma unroll 4
    for (int i = 0; i < 16; ++i) {
        const float4 vv = v0, sv = s0;
        v0 = v1; s0 = s1;
        if (i < 14) {
            const size_t nb = base + (size_t)(i + 2) * 256;
            v1 = *reinterpret_cast<const float4*>(vol  + nb);
            s1 = *reinterpret_cast<const float4*>(cons + nb);
        }
        const unsigned nib = ((vv.x > PERM_THR || sv.x > PERM_THR) ? 1u : 0u)
                           | ((vv.y > PERM_THR || sv.y > PERM_THR) ? 2u : 0u)
                           | ((vv.z > PERM_THR || sv.z > PERM_THR) ? 4u : 0u)
                           | ((vv.w > PERM_THR || sv.w > PERM_THR) ? 8u : 0u);
        bits |= ((unsigned long long)nib) << (4 * i);
    }
    conbits[(size_t)cell * 64 + lane] = bits;
}

// ---------------------------------------------------------------------------
// Kernel 3: phase 1 — one wave per cell, single conn stream (int4/lane) with
// 2-deep rotating prefetch + one 8B conbits load. Running first-argmax key.
// ---------------------------------------------------------------------------
__global__ __launch_bounds__(256) void phase1b_kernel(const int* __restrict__ conn,
                                                      const unsigned long long* __restrict__ conbits,
                                                      unsigned* __restrict__ ws) {
    __shared__ unsigned prevmask[512];
    const int tid = threadIdx.x;
    for (int i = tid; i < 512; i += 256) prevmask[i] = ws[WS_PREVMASK + i];
    __syncthreads();

    const int wave = tid >> 6;
    const int lane = tid & 63;
    const int half = lane >> 5;
    const int l32  = lane & 31;
    const int sh   = half * 32;
    const int cell = blockIdx.x * 4 + wave;
    const size_t base = (size_t)cell * (S_ * Y_) + (size_t)half * Y_ + (size_t)(l32 * 4);

    unsigned long long bits = conbits[(size_t)cell * 64 + lane];
    int4 a0 = *reinterpret_cast<const int4*>(conn + base);
    int4 a1 = *reinterpret_cast<const int4*>(conn + base + 256);

    unsigned key = 0u;
    bool predf = false;

    #pragma unroll 4
    for (int i = 0; i < 16; ++i) {
        const int4 cv = a0;
        a0 = a1;
        if (i < 14) a1 = *reinterpret_cast<const int4*>(conn + base + (size_t)(i + 2) * 256);

        const unsigned nib = (unsigned)bits & 0xFu;
        bits >>= 4;

        const int m0 = min(max(cv.x, 0), N_ - 1);
        const int m1 = min(max(cv.y, 0), N_ - 1);
        const int m2 = min(max(cv.z, 0), N_ - 1);
        const int m3 = min(max(cv.w, 0), N_ - 1);
        const bool p0 = (prevmask[m0 >> 5] >> (m0 & 31)) & 1u;
        const bool p1 = (prevmask[m1 >> 5] >> (m1 & 31)) & 1u;
        const bool p2 = (prevmask[m2 >> 5] >> (m2 & 31)) & 1u;
        const bool p3 = (prevmask[m3 >> 5] >> (m3 & 31)) & 1u;
        const bool c0 = nib & 1u;
        const bool c1 = nib & 2u;
        const bool c2 = nib & 4u;
        const bool c3 = nib & 8u;

        const uint64_t bp0 = __ballot(p0), bp1 = __ballot(p1),
                       bp2 = __ballot(p2), bp3 = __ballot(p3);
        const uint64_t ba0 = __ballot(p0 && c0), ba1 = __ballot(p1 && c1),
                       ba2 = __ballot(p2 && c2), ba3 = __ballot(p3 && c3);

        const int ov = __popc((unsigned)(bp0 >> sh)) + __popc((unsigned)(bp1 >> sh)) +
                       __popc((unsigned)(bp2 >> sh)) + __popc((unsigned)(bp3 >> sh));
        const int ac = __popc((unsigned)(ba0 >> sh)) + __popc((unsigned)(ba1 >> sh)) +
                       __popc((unsigned)(ba2 >> sh)) + __popc((unsigned)(ba3 >> sh));

        predf |= (ac >= ACT_THR);
        const int seg = 2 * i + half;
        const unsigned k2 = ((unsigned)ov << 6) | (unsigned)(63 - seg);
        key = max(key, k2);                 // max(ov, then smallest seg) == first argmax
    }

    const unsigned okey = (unsigned)__shfl_xor((int)key, 32);
    const unsigned fkey = max(key, okey);
    const bool fpred = (__any(predf ? 1 : 0) != 0);
    if (lane == 0) {
        const int bo = (int)(fkey >> 6);
        const int bs = 63 - (int)(fkey & 63u);
        ws[WS_CELLINFO + cell] = (fpred ? 1u : 0u) | ((unsigned)bs << 8) | ((unsigned)bo << 16);
    }
}

// ---------------------------------------------------------------------------
// Kernel 4: per-column logic — predicted / burst winner / new_active output,
// learn list, counters, burst-column bitmask. (unchanged)
// ---------------------------------------------------------------------------
__global__ __launch_bounds__(256) void column_kernel(const int* __restrict__ x,
                                                     unsigned*  __restrict__ ws,
                                                     float*     __restrict__ out_new_active) {
    const int c = blockIdx.x * 256 + threadIdx.x;
    if (c >= C_) return;
    const bool xa = (x[c] != 0);
    const int base = c * K_;

    unsigned info[K_];
    bool colpred = false;
    int bo = -1, bk = 0;
    #pragma unroll
    for (int k = 0; k < K_; ++k) {
        const unsigned inf = ws[WS_CELLINFO + base + k];
        info[k] = inf;
        if (inf & 1u) colpred = true;
        const int ov = (int)((inf >> 16) & 0xFFu);
        if (ov > bo) { bo = ov; bk = k; }   // strict > keeps first (k,s) flat argmax
    }

    const bool burst = xa && !colpred;
    const float nav = burst ? 1.0f : 0.0f;
    #pragma unroll
    for (int k = 0; k < K_; ++k) out_new_active[base + k] = nav;

    if (xa) {
        atomicAdd(&ws[WS_NUM_ACTIVE], 1u);
        if (colpred) atomicAdd(&ws[WS_NUM_PRED], 1u);
    }
    if (burst) {
        atomicAdd(&ws[WS_NBURST], 1u);
        atomicOr(&ws[WS_BURSTMASK + (c >> 5)], 1u << (c & 31));
    }
    if (xa) {
        if (colpred) {
            #pragma unroll
            for (int k = 0; k < K_; ++k) {
                if (info[k] & 1u) {
                    const unsigned i = atomicAdd(&ws[WS_LEARN_CNT], 1u);
                    ws[WS_LIST + i] = (unsigned)(base + k);
                }
            }
        } else {
            const unsigned i = atomicAdd(&ws[WS_LEARN_CNT], 1u);
            ws[WS_LIST + i] = (unsigned)(base + bk);
        }
    }
}

// ---------------------------------------------------------------------------
// Kernel 5: learning — update vol on each winner's best segment AND patch the
// connected-bit table so phase2 sees connected2 exactly. Half-wave per entry,
// 4 synapses/lane (float4). Also writes acc.
// ---------------------------------------------------------------------------
__global__ __launch_bounds__(256) void learnb_kernel(const int*   __restrict__ conn,
                                                     float*       __restrict__ vol,
                                                     const float* __restrict__ cons,
                                                     unsigned*    __restrict__ ws,
                                                     float*       __restrict__ out_acc) {
    __shared__ unsigned prevmask[512];
    const int tid = threadIdx.x;
    for (int i = tid; i < 512; i += 256) prevmask[i] = ws[WS_PREVMASK + i];
    __syncthreads();

    if (blockIdx.x == 0 && tid == 0) {
        const int na  = (int)ws[WS_NUM_ACTIVE];
        const int np_ = (int)ws[WS_NUM_PRED];
        out_acc[0] = (na > 0) ? ((float)np_ / (float)na) : 1.0f;
    }
    if (ws[WS_PREV_ANY] == 0u) return;   // torch skips learning if no prev activity

    const int cnt = (int)ws[WS_LEARN_CNT];
    const int hw  = (blockIdx.x * 256 + tid) >> 5;   // half-wave id (32 lanes)
    const int g   = tid & 31;
    const int nhw = gridDim.x * 8;
    unsigned* conbits32 = ws + WS_CONBITS;

    for (int e = hw; e < cnt; e += nhw) {
        const int cellv = (int)ws[WS_LIST + e];
        const int seg   = (int)((ws[WS_CELLINFO + cellv] >> 8) & 0xFFu);
        const size_t base = ((size_t)cellv * S_ + seg) * Y_ + (size_t)(g * 4);
        const int4   cv = *reinterpret_cast<const int4*>(conn + base);
        float4       vv = *reinterpret_cast<float4*>(vol + base);
        const float4 sv = *reinterpret_cast<const float4*>(cons + base);
        const int m0 = min(max(cv.x, 0), N_ - 1);
        const int m1 = min(max(cv.y, 0), N_ - 1);
        const int m2 = min(max(cv.z, 0), N_ - 1);
        const int m3 = min(max(cv.w, 0), N_ - 1);
        const bool p0 = (prevmask[m0 >> 5] >> (m0 & 31)) & 1u;
        const bool p1 = (prevmask[m1 >> 5] >> (m1 & 31)) & 1u;
        const bool p2 = (prevmask[m2 >> 5] >> (m2 & 31)) & 1u;
        const bool p3 = (prevmask[m3 >> 5] >> (m3 & 31)) & 1u;
        vv.x = fminf(fmaxf(vv.x + (p0 ? POT : -PUN), 0.0f), 1.0f);
        vv.y = fminf(fmaxf(vv.y + (p1 ? POT : -PUN), 0.0f), 1.0f);
        vv.z = fminf(fmaxf(vv.z + (p2 ? POT : -PUN), 0.0f), 1.0f);
        vv.w = fminf(fmaxf(vv.w + (p3 ? POT : -PUN), 0.0f), 1.0f);
        *reinterpret_cast<float4*>(vol + base) = vv;

        // patch connected nibble for this (cell, seg, group g)
        const unsigned nib = ((vv.x > PERM_THR || sv.x > PERM_THR) ? 1u : 0u)
                           | ((vv.y > PERM_THR || sv.y > PERM_THR) ? 2u : 0u)
                           | ((vv.z > PERM_THR || sv.z > PERM_THR) ? 4u : 0u)
                           | ((vv.w > PERM_THR || sv.w > PERM_THR) ? 8u : 0u);
        const int chunk = seg >> 1;
        const int slot  = (seg & 1) * 32 + g;                  // lane index in conbits layout
        const unsigned idx = (unsigned)(cellv * 128 + slot * 2 + (chunk >> 3));
        const int shn = 4 * (chunk & 7);
        const unsigned old = conbits32[idx];
        conbits32[idx] = (old & ~(0xFu << shn)) | (nib << shn);  // unique cell per entry: no race
    }
}

// ---------------------------------------------------------------------------
// Kernel 6: phase 2 — conn stream + conbits, presyn = burst[col(m)].
// Block-level early exit when no column bursts.
// ---------------------------------------------------------------------------
__global__ __launch_bounds__(256) void phase2b_kernel(const int* __restrict__ conn,
                                                      const unsigned long long* __restrict__ conbits,
                                                      const unsigned* __restrict__ ws,
                                                      float* __restrict__ out_pred_next) {
    __shared__ unsigned nburst_s;
    __shared__ unsigned burstmask[32];
    const int tid = threadIdx.x;
    if (tid == 0) nburst_s = ws[WS_NBURST];
    if (tid >= 64 && tid < 96) burstmask[tid - 64] = ws[WS_BURSTMASK + (tid - 64)];
    __syncthreads();

    const int cbase = blockIdx.x * 4;
    if (nburst_s == 0u) {                       // uniform: no bursting columns
        if (tid < 4) out_pred_next[cbase + tid] = 0.0f;
        return;
    }

    const int wave = tid >> 6;
    const int lane = tid & 63;
    const int half = lane >> 5;
    const int l32  = lane & 31;
    const int sh   = half * 32;
    const int cell = cbase + wave;
    const size_t base = (size_t)cell * (S_ * Y_) + (size_t)half * Y_ + (size_t)(l32 * 4);

    unsigned long long bits = conbits[(size_t)cell * 64 + lane];
    int4 a0 = *reinterpret_cast<const int4*>(conn + base);
    int4 a1 = *reinterpret_cast<const int4*>(conn + base + 256);

    bool predf = false;

    #pragma unroll 4
    for (int i = 0; i < 16; ++i) {
        const int4 cv = a0;
        a0 = a1;
        if (i < 14) a1 = *reinterpret_cast<const int4*>(conn + base + (size_t)(i + 2) * 256);

        const unsigned nib = (unsigned)bits & 0xFu;
        bits >>= 4;

        const int m0 = min(max(cv.x, 0), N_ - 1) >> 4;   // presyn column id
        const int m1 = min(max(cv.y, 0), N_ - 1) >> 4;
        const int m2 = min(max(cv.z, 0), N_ - 1) >> 4;
        const int m3 = min(max(cv.w, 0), N_ - 1) >> 4;
        const bool p0 = (burstmask[m0 >> 5] >> (m0 & 31)) & 1u;
        const bool p1 = (burstmask[m1 >> 5] >> (m1 & 31)) & 1u;
        const bool p2 = (burstmask[m2 >> 5] >> (m2 & 31)) & 1u;
        const bool p3 = (burstmask[m3 >> 5] >> (m3 & 31)) & 1u;
        const bool c0 = nib & 1u;
        const bool c1 = nib & 2u;
        const bool c2 = nib & 4u;
        const bool c3 = nib & 8u;

        const uint64_t ba0 = __ballot(p0 && c0), ba1 = __ballot(p1 && c1),
                       ba2 = __ballot(p2 && c2), ba3 = __ballot(p3 && c3);
        const int ac = __popc((unsigned)(ba0 >> sh)) + __popc((unsigned)(ba1 >> sh)) +
                       __popc((unsigned)(ba2 >> sh)) + __popc((unsigned)(ba3 >> sh));
        predf |= (ac >= ACT_THR);
    }

    const bool fpred = (__any(predf ? 1 : 0) != 0);
    if (lane == 0) out_pred_next[cell] = fpred ? 1.0f : 0.0f;
}

// ===========================================================================
// Fallback path (workspace too small for conbits): previous verified pipeline.
// ===========================================================================
__global__ __launch_bounds__(256) void phase1_old(const int*   __restrict__ conn,
                                                  const float* __restrict__ vol,
                                                  const float* __restrict__ cons,
                                                  unsigned*    __restrict__ ws) {
    __shared__ unsigned prevmask[512];
    const int tid = threadIdx.x;
    for (int i = tid; i < 512; i += 256) prevmask[i] = ws[WS_PREVMASK + i];
    __syncthreads();

    const int wave = tid >> 6;
    const int lane = tid & 63;
    const int half = lane >> 5;
    const int l32  = lane & 31;
    const int sh   = half * 32;

    #pragma unroll 1
    for (int ci = 0; ci < 2; ++ci) {
        const int cell = blockIdx.x * 8 + wave + ci * 4;
        const size_t cellbase = (size_t)cell * (S_ * Y_) + (size_t)(l32 * 4);

        size_t a = cellbase + (size_t)half * Y_;
        int4   cv_n = *reinterpret_cast<const int4*>(conn + a);
        float4 vv_n = *reinterpret_cast<const float4*>(vol + a);
        float4 sv_n = *reinterpret_cast<const float4*>(cons + a);

        unsigned key = 0u;
        bool predf = false;

        #pragma unroll 2
        for (int i = 0; i < 16; ++i) {
            const int4   cv = cv_n;
            const float4 vv = vv_n;
            const float4 sv = sv_n;
            if (i < 15) {
                const size_t nb = cellbase + (size_t)(2 * (i + 1) + half) * Y_;
                cv_n = *reinterpret_cast<const int4*>(conn + nb);
                vv_n = *reinterpret_cast<const float4*>(vol + nb);
                sv_n = *reinterpret_cast<const float4*>(cons + nb);
            }

            const int m0 = min(max(cv.x, 0), N_ - 1);
            const int m1 = min(max(cv.y, 0), N_ - 1);
            const int m2 = min(max(cv.z, 0), N_ - 1);
            const int m3 = min(max(cv.w, 0), N_ - 1);
            const bool p0 = (prevmask[m0 >> 5] >> (m0 & 31)) & 1u;
            const bool p1 = (prevmask[m1 >> 5] >> (m1 & 31)) & 1u;
            const bool p2 = (prevmask[m2 >> 5] >> (m2 & 31)) & 1u;
            const bool p3 = (prevmask[m3 >> 5] >> (m3 & 31)) & 1u;
            const bool c0 = (vv.x > PERM_THR) || (sv.x > PERM_THR);
            const bool c1 = (vv.y > PERM_THR) || (sv.y > PERM_THR);
            const bool c2 = (vv.z > PERM_THR) || (sv.z > PERM_THR);
            const bool c3 = (vv.w > PERM_THR) || (sv.w > PERM_THR);

            const uint64_t bp0 = __ballot(p0), bp1 = __ballot(p1),
                           bp2 = __ballot(p2), bp3 = __ballot(p3);
            const uint64_t ba0 = __ballot(p0 && c0), ba1 = __ballot(p1 && c1),
                           ba2 = __ballot(p2 && c2), ba3 = __ballot(p3 && c3);

            const int ov = __popc((unsigned)(bp0 >> sh)) + __popc((unsigned)(bp1 >> sh)) +
                           __popc((unsigned)(bp2 >> sh)) + __popc((unsigned)(bp3 >> sh));
            const int ac = __popc((unsigned)(ba0 >> sh)) + __popc((unsigned)(ba1 >> sh)) +
                           __popc((unsigned)(ba2 >> sh)) + __popc((unsigned)(ba3 >> sh));

            predf |= (ac >= ACT_THR);
            const int seg = 2 * i + half;
            const unsigned k2 = ((unsigned)ov << 6) | (unsigned)(63 - seg);
            key = max(key, k2);
        }

        const unsigned okey = (unsigned)__shfl_xor((int)key, 32);
        const unsigned fkey = max(key, okey);
        const bool fpred = (__any(predf ? 1 : 0) != 0);
        if (lane == 0) {
            const int bo = (int)(fkey >> 6);
            const int bs = 63 - (int)(fkey & 63u);
            ws[WS_CELLINFO + cell] = (fpred ? 1u : 0u) | ((unsigned)bs << 8) | ((unsigned)bo << 16);
        }
    }
}

__global__ __launch_bounds__(256) void learn_old(const int* __restrict__ conn,
                                                 float*     __restrict__ vol,
                                                 unsigned*  __restrict__ ws,
                                                 float*     __restrict__ out_acc) {
    __shared__ unsigned prevmask[512];
    const int tid = threadIdx.x;
    for (int i = tid; i < 512; i += 256) prevmask[i] = ws[WS_PREVMASK + i];
    __syncthreads();

    if (blockIdx.x == 0 && tid == 0) {
        const int na  = (int)ws[WS_NUM_ACTIVE];
        const int np_ = (int)ws[WS_NUM_PRED];
        out_acc[0] = (na > 0) ? ((float)np_ / (float)na) : 1.0f;
    }
    if (ws[WS_PREV_ANY] == 0u) return;

    const int cnt    = (int)ws[WS_LEARN_CNT];
    const int wave   = (blockIdx.x * 256 + tid) >> 6;
    const int lane   = tid & 63;
    const int nwaves = gridDim.x * 4;

    for (int e = wave; e < cnt; e += nwaves) {
        const int cell = (int)ws[WS_LIST + e];
        const int seg  = (int)((ws[WS_CELLINFO + cell] >> 8) & 0xFFu);
        const size_t base = ((size_t)cell * S_ + seg) * Y_ + (size_t)(lane * 2);
        const int2 cv = *reinterpret_cast<const int2*>(conn + base);
        float2 vv = *reinterpret_cast<const float2*>(vol + base);
        const int m0 = min(max(cv.x, 0), N_ - 1);
        const int m1 = min(max(cv.y, 0), N_ - 1);
        const bool p0 = (prevmask[m0 >> 5] >> (m0 & 31)) & 1u;
        const bool p1 = (prevmask[m1 >> 5] >> (m1 & 31)) & 1u;
        vv.x = fminf(fmaxf(vv.x + (p0 ? POT : -PUN), 0.0f), 1.0f);
        vv.y = fminf(fmaxf(vv.y + (p1 ? POT : -PUN), 0.0f), 1.0f);
        *reinterpret_cast<float2*>(vol + base) = vv;
    }
}

__global__ __launch_bounds__(256) void phase2_old(const int*   __restrict__ conn,
                                                  const float* __restrict__ vol,
                                                  const float* __restrict__ cons,
                                                  const unsigned* __restrict__ ws,
                                                  float* __restrict__ out_pred_next) {
    __shared__ unsigned nburst_s;
    __shared__ unsigned burstmask[32];
    const int tid = threadIdx.x;
    if (tid == 0) nburst_s = ws[WS_NBURST];
    if (tid >= 64 && tid < 96) burstmask[tid - 64] = ws[WS_BURSTMASK + (tid - 64)];
    __syncthreads();

    const int cbase = blockIdx.x * 8;
    if (nburst_s == 0u) {
        if (tid < 8) out_pred_next[cbase + tid] = 0.0f;
        return;
    }

    const int wave = tid >> 6;
    const int lane = tid & 63;
    const int half = lane >> 5;
    const int l32  = lane & 31;
    const int sh   = half * 32;

    #pragma unroll 1
    for (int ci = 0; ci < 2; ++ci) {
        const int cell = cbase + wave + ci * 4;
        const size_t cellbase = (size_t)cell * (S_ * Y_) + (size_t)(l32 * 4);

        size_t a = cellbase + (size_t)half * Y_;
        int4   cv_n = *reinterpret_cast<const int4*>(conn + a);
        float4 vv_n = *reinterpret_cast<const float4*>(vol + a);
        float4 sv_n = *reinterpret_cast<const float4*>(cons + a);

        bool predf = false;

        #pragma unroll 2
        for (int i = 0; i < 16; ++i) {
            const int4   cv = cv_n;
            const float4 vv = vv_n;
            const float4 sv = sv_n;
            if (i < 15) {
                const size_t nb = cellbase + (size_t)(2 * (i + 1) + half) * Y_;
                cv_n = *reinterpret_cast<const int4*>(conn + nb);
                vv_n = *reinterpret_cast<const float4*>(vol + nb);
                sv_n = *reinterpret_cast<const float4*>(cons + nb);
            }

            const int m0 = min(max(cv.x, 0), N_ - 1) >> 4;
            const int m1 = min(max(cv.y, 0), N_ - 1) >> 4;
            const int m2 = min(max(cv.z, 0), N_ - 1) >> 4;
            const int m3 = min(max(cv.w, 0), N_ - 1) >> 4;
            const bool p0 = (burstmask[m0 >> 5] >> (m0 & 31)) & 1u;
            const bool p1 = (burstmask[m1 >> 5] >> (m1 & 31)) & 1u;
            const bool p2 = (burstmask[m2 >> 5] >> (m2 & 31)) & 1u;
            const bool p3 = (burstmask[m3 >> 5] >> (m3 & 31)) & 1u;
            const bool c0 = (vv.x > PERM_THR) || (sv.x > PERM_THR);
            const bool c1 = (vv.y > PERM_THR) || (sv.y > PERM_THR);
            const bool c2 = (vv.z > PERM_THR) || (sv.z > PERM_THR);
            const bool c3 = (vv.w > PERM_THR) || (sv.w > PERM_THR);

            const uint64_t ba0 = __ballot(p0 && c0), ba1 = __ballot(p1 && c1),
                           ba2 = __ballot(p2 && c2), ba3 = __ballot(p3 && c3);
            const int ac = __popc((unsigned)(ba0 >> sh)) + __popc((unsigned)(ba1 >> sh)) +
                           __popc((unsigned)(ba2 >> sh)) + __popc((unsigned)(ba3 >> sh));
            predf |= (ac >= ACT_THR);
        }

        const bool fpred = (__any(predf ? 1 : 0) != 0);
        if (lane == 0) out_pred_next[cell] = fpred ? 1.0f : 0.0f;
    }
}

// ---------------------------------------------------------------------------
extern "C" void kernel_launch(void* const* d_in, const int* in_sizes, int n_in,
                              void* d_out, int out_size, void* d_ws, size_t ws_size,
                              hipStream_t stream) {
    const int*   x    = (const int*)d_in[0];
    const int*   prev = (const int*)d_in[1];
    const int*   conn = (const int*)d_in[2];
    float*       vol  = (float*)d_in[3];        // updated in place (restored by harness)
    const float* cons = (const float*)d_in[4];
    float*    out = (float*)d_out;              // [0..N): new_active, [N..2N): pred_next, [2N]: acc
    unsigned* ws  = (unsigned*)d_ws;

    const size_t need = (size_t)WS_CONBITS * 4 + (size_t)N_ * 64 * 8;  // 256KB + 8MB

    pack_kernel<<<1, 512, 0, stream>>>(prev, ws);

    if (ws_size >= need) {
        unsigned long long* conbits = (unsigned long long*)(ws + WS_CONBITS);
        precompute_kernel<<<N_ / 4, 256, 0, stream>>>(vol, cons, conbits);
        phase1b_kernel   <<<N_ / 4, 256, 0, stream>>>(conn, conbits, ws);
        column_kernel    <<<C_ / 256, 256, 0, stream>>>(x, ws, out);
        learnb_kernel    <<<64, 256, 0, stream>>>(conn, vol, cons, ws, out + 2 * N_);
        phase2b_kernel   <<<N_ / 4, 256, 0, stream>>>(conn, conbits, ws, out + N_);
    } else {
        phase1_old<<<2048, 256, 0, stream>>>(conn, vol, cons, ws);
        column_kernel<<<C_ / 256, 256, 0, stream>>>(x, ws, out);
        learn_old<<<64, 256, 0, stream>>>(conn, vol, ws, out + 2 * N_);
        phase2_old<<<2048, 256, 0, stream>>>(conn, vol, cons, ws, out + N_);
    }
}

// Round 2
// 667.477 us; speedup vs baseline: 1.0196x; 1.0196x over previous
//
#include <hip/hip_runtime.h>
#include <stdint.h>

#define C_ 1024
#define K_ 16
#define S_ 32
#define Y_ 128
#define N_ (C_ * K_)          // 16384 cells
#define ACT_THR 10
#define PERM_THR 0.5f
#define POT 0.1f              // LR * MOD
#define PUN 0.01f             // POT * 0.1

typedef float f4 __attribute__((ext_vector_type(4)));
typedef int   i4 __attribute__((ext_vector_type(4)));

// ---- workspace layout (u32 indices) ----
#define WS_NUM_ACTIVE 0
#define WS_NUM_PRED   1
#define WS_NBURST     2
#define WS_LEARN_CNT  3
#define WS_PREV_ANY   4
#define WS_BURSTMASK  8        // 32 words  (1024 column bits)
#define WS_PREVMASK   64       // 512 words (16384 cell bits)
#define WS_CELLINFO   1024     // N words: pred(1b) | best_seg<<8 | best_overlap<<16
#define WS_LIST       (1024 + N_) // up to N winner-cell ids
#define WS_CONBITS    65536    // word offset (256KB): N*64 u64 = 8 MB connected-bit table

// conbits layout: u64 per (cell, lane). Bit 4*i+e of conbits[cell*64+lane] =
// connected bit for synapse (lane&31)*4+e of segment 2*i+(lane>>5) of cell.

// ---------------------------------------------------------------------------
// Kernel 1: pack prev_active bits into ws bitmask, zero counters, prev_any.
// ---------------------------------------------------------------------------
__global__ __launch_bounds__(512) void pack_kernel(const int* __restrict__ prev,
                                                   unsigned* __restrict__ ws) {
    const int tid = threadIdx.x;
    if (tid < 64) ws[tid] = 0u;   // counters + burst mask
    __syncthreads();
    const int4* p = reinterpret_cast<const int4*>(prev + tid * 32);
    unsigned m = 0u;
    #pragma unroll
    for (int q = 0; q < 8; ++q) {
        const int4 v = p[q];
        m |= (v.x != 0 ? 1u : 0u) << (q * 4 + 0);
        m |= (v.y != 0 ? 1u : 0u) << (q * 4 + 1);
        m |= (v.z != 0 ? 1u : 0u) << (q * 4 + 2);
        m |= (v.w != 0 ? 1u : 0u) << (q * 4 + 3);
    }
    ws[WS_PREVMASK + tid] = m;
    const bool any = (__ballot(m != 0u) != 0ull);
    if ((tid & 63) == 0 && any) atomicOr(&ws[WS_PREV_ANY], 1u);
}

// ---------------------------------------------------------------------------
// Kernel 2: fused phase1 + connected-bit build. One wave = 2 cells interleaved
// (6 independent 16B load streams), peeled software pipeline (all prefetches
// unconditional + in-bounds). vol/cons nontemporal (stream-once; keep conn in
// L3 for phase2's re-read). Emits cellinfo + conbits.
// ---------------------------------------------------------------------------
__global__ __launch_bounds__(256) void phase1c_kernel(const int*   __restrict__ conn,
                                                      const float* __restrict__ vol,
                                                      const float* __restrict__ cons,
                                                      unsigned long long* __restrict__ conbits,
                                                      unsigned*    __restrict__ ws) {
    __shared__ unsigned prevmask[512];
    const int tid = threadIdx.x;
    for (int i = tid; i < 512; i += 256) prevmask[i] = ws[WS_PREVMASK + i];
    __syncthreads();

    const int wave = tid >> 6;
    const int lane = tid & 63;
    const int half = lane >> 5;
    const int l32  = lane & 31;
    const int sh   = half * 32;

    const int cellA = blockIdx.x * 8 + wave;
    const int cellB = cellA + 4;
    const size_t baseA = (size_t)cellA * (S_ * Y_) + (size_t)half * Y_ + (size_t)(l32 * 4);
    const size_t baseB = (size_t)cellB * (S_ * Y_) + (size_t)half * Y_ + (size_t)(l32 * 4);

    // per-chunk processing: overlap/active ballots + running argmax key + conbits
    auto proc = [&](const i4 cv, const f4 vv, const f4 sv, const int i,
                    unsigned& key, bool& predf, unsigned long long& bits) {
        const unsigned nib = ((vv[0] > PERM_THR || sv[0] > PERM_THR) ? 1u : 0u)
                           | ((vv[1] > PERM_THR || sv[1] > PERM_THR) ? 2u : 0u)
                           | ((vv[2] > PERM_THR || sv[2] > PERM_THR) ? 4u : 0u)
                           | ((vv[3] > PERM_THR || sv[3] > PERM_THR) ? 8u : 0u);
        bits |= ((unsigned long long)nib) << (4 * i);

        const int m0 = min(max(cv[0], 0), N_ - 1);
        const int m1 = min(max(cv[1], 0), N_ - 1);
        const int m2 = min(max(cv[2], 0), N_ - 1);
        const int m3 = min(max(cv[3], 0), N_ - 1);
        const bool p0 = (prevmask[m0 >> 5] >> (m0 & 31)) & 1u;
        const bool p1 = (prevmask[m1 >> 5] >> (m1 & 31)) & 1u;
        const bool p2 = (prevmask[m2 >> 5] >> (m2 & 31)) & 1u;
        const bool p3 = (prevmask[m3 >> 5] >> (m3 & 31)) & 1u;

        const uint64_t bp0 = __ballot(p0), bp1 = __ballot(p1),
                       bp2 = __ballot(p2), bp3 = __ballot(p3);
        const uint64_t ba0 = __ballot(p0 && (nib & 1u)), ba1 = __ballot(p1 && (nib & 2u)),
                       ba2 = __ballot(p2 && (nib & 4u)), ba3 = __ballot(p3 && (nib & 8u));

        const int ov = __popc((unsigned)(bp0 >> sh)) + __popc((unsigned)(bp1 >> sh)) +
                       __popc((unsigned)(bp2 >> sh)) + __popc((unsigned)(bp3 >> sh));
        const int ac = __popc((unsigned)(ba0 >> sh)) + __popc((unsigned)(ba1 >> sh)) +
                       __popc((unsigned)(ba2 >> sh)) + __popc((unsigned)(ba3 >> sh));

        predf |= (ac >= ACT_THR);
        const int seg = 2 * i + half;
        const unsigned k2 = ((unsigned)ov << 6) | (unsigned)(63 - seg);
        key = max(key, k2);                 // max(ov, then smallest seg) == first argmax
    };

    // prologue: iter-0 loads for both cells (6 streams)
    i4 cA = *reinterpret_cast<const i4*>(conn + baseA);
    i4 cB = *reinterpret_cast<const i4*>(conn + baseB);
    f4 vA = __builtin_nontemporal_load(reinterpret_cast<const f4*>(vol  + baseA));
    f4 vB = __builtin_nontemporal_load(reinterpret_cast<const f4*>(vol  + baseB));
    f4 sA = __builtin_nontemporal_load(reinterpret_cast<const f4*>(cons + baseA));
    f4 sB = __builtin_nontemporal_load(reinterpret_cast<const f4*>(cons + baseB));

    unsigned keyA = 0u, keyB = 0u;
    bool pfA = false, pfB = false;
    unsigned long long bitsA = 0ull, bitsB = 0ull;

    #pragma unroll 3
    for (int i = 0; i < 15; ++i) {
        // issue iter i+1 loads for both cells first — 6 independent loads,
        // always within the cell's own 4096-elem row (no bounds check needed)
        const size_t nA = baseA + (size_t)(i + 1) * 256;
        const size_t nB = baseB + (size_t)(i + 1) * 256;
        const i4 cA1 = *reinterpret_cast<const i4*>(conn + nA);
        const i4 cB1 = *reinterpret_cast<const i4*>(conn + nB);
        const f4 vA1 = __builtin_nontemporal_load(reinterpret_cast<const f4*>(vol  + nA));
        const f4 vB1 = __builtin_nontemporal_load(reinterpret_cast<const f4*>(vol  + nB));
        const f4 sA1 = __builtin_nontemporal_load(reinterpret_cast<const f4*>(cons + nA));
        const f4 sB1 = __builtin_nontemporal_load(reinterpret_cast<const f4*>(cons + nB));

        proc(cA, vA, sA, i, keyA, pfA, bitsA);
        proc(cB, vB, sB, i, keyB, pfB, bitsB);

        cA = cA1; vA = vA1; sA = sA1;
        cB = cB1; vB = vB1; sB = sB1;
    }
    // peeled last iteration (no prefetch)
    proc(cA, vA, sA, 15, keyA, pfA, bitsA);
    proc(cB, vB, sB, 15, keyB, pfB, bitsB);

    // reduce + write
    const unsigned fkA = max(keyA, (unsigned)__shfl_xor((int)keyA, 32));
    const unsigned fkB = max(keyB, (unsigned)__shfl_xor((int)keyB, 32));
    const bool fpA = (__any(pfA ? 1 : 0) != 0);
    const bool fpB = (__any(pfB ? 1 : 0) != 0);
    if (lane == 0) {
        ws[WS_CELLINFO + cellA] = (fpA ? 1u : 0u) | ((unsigned)(63 - (fkA & 63u)) << 8) | ((fkA >> 6) << 16);
        ws[WS_CELLINFO + cellB] = (fpB ? 1u : 0u) | ((unsigned)(63 - (fkB & 63u)) << 8) | ((fkB >> 6) << 16);
    }
    conbits[(size_t)cellA * 64 + lane] = bitsA;
    conbits[(size_t)cellB * 64 + lane] = bitsB;
}

// ---------------------------------------------------------------------------
// Kernel 3: per-column logic — predicted / burst winner / new_active output,
// learn list, counters, burst-column bitmask.
// ---------------------------------------------------------------------------
__global__ __launch_bounds__(256) void column_kernel(const int* __restrict__ x,
                                                     unsigned*  __restrict__ ws,
                                                     float*     __restrict__ out_new_active) {
    const int c = blockIdx.x * 256 + threadIdx.x;
    if (c >= C_) return;
    const bool xa = (x[c] != 0);
    const int base = c * K_;

    unsigned info[K_];
    bool colpred = false;
    int bo = -1, bk = 0;
    #pragma unroll
    for (int k = 0; k < K_; ++k) {
        const unsigned inf = ws[WS_CELLINFO + base + k];
        info[k] = inf;
        if (inf & 1u) colpred = true;
        const int ov = (int)((inf >> 16) & 0xFFu);
        if (ov > bo) { bo = ov; bk = k; }   // strict > keeps first (k,s) flat argmax
    }

    const bool burst = xa && !colpred;
    const float nav = burst ? 1.0f : 0.0f;
    #pragma unroll
    for (int k = 0; k < K_; ++k) out_new_active[base + k] = nav;

    if (xa) {
        atomicAdd(&ws[WS_NUM_ACTIVE], 1u);
        if (colpred) atomicAdd(&ws[WS_NUM_PRED], 1u);
    }
    if (burst) {
        atomicAdd(&ws[WS_NBURST], 1u);
        atomicOr(&ws[WS_BURSTMASK + (c >> 5)], 1u << (c & 31));
    }
    if (xa) {
        if (colpred) {
            #pragma unroll
            for (int k = 0; k < K_; ++k) {
                if (info[k] & 1u) {
                    const unsigned i = atomicAdd(&ws[WS_LEARN_CNT], 1u);
                    ws[WS_LIST + i] = (unsigned)(base + k);
                }
            }
        } else {
            const unsigned i = atomicAdd(&ws[WS_LEARN_CNT], 1u);
            ws[WS_LIST + i] = (unsigned)(base + bk);
        }
    }
}

// ---------------------------------------------------------------------------
// Kernel 4: learning — update vol on each winner's best segment AND patch the
// connected-bit table so phase2 sees connected2 exactly. Half-wave per entry.
// ---------------------------------------------------------------------------
__global__ __launch_bounds__(256) void learnb_kernel(const int*   __restrict__ conn,
                                                     float*       __restrict__ vol,
                                                     const float* __restrict__ cons,
                                                     unsigned*    __restrict__ ws,
                                                     float*       __restrict__ out_acc) {
    __shared__ unsigned prevmask[512];
    const int tid = threadIdx.x;
    for (int i = tid; i < 512; i += 256) prevmask[i] = ws[WS_PREVMASK + i];
    __syncthreads();

    if (blockIdx.x == 0 && tid == 0) {
        const int na  = (int)ws[WS_NUM_ACTIVE];
        const int np_ = (int)ws[WS_NUM_PRED];
        out_acc[0] = (na > 0) ? ((float)np_ / (float)na) : 1.0f;
    }
    if (ws[WS_PREV_ANY] == 0u) return;   // torch skips learning if no prev activity

    const int cnt = (int)ws[WS_LEARN_CNT];
    const int hw  = (blockIdx.x * 256 + tid) >> 5;   // half-wave id (32 lanes)
    const int g   = tid & 31;
    const int nhw = gridDim.x * 8;
    unsigned* conbits32 = ws + WS_CONBITS;

    for (int e = hw; e < cnt; e += nhw) {
        const int cellv = (int)ws[WS_LIST + e];
        const int seg   = (int)((ws[WS_CELLINFO + cellv] >> 8) & 0xFFu);
        const size_t base = ((size_t)cellv * S_ + seg) * Y_ + (size_t)(g * 4);
        const int4   cv = *reinterpret_cast<const int4*>(conn + base);
        float4       vv = *reinterpret_cast<float4*>(vol + base);
        const float4 sv = *reinterpret_cast<const float4*>(cons + base);
        const int m0 = min(max(cv.x, 0), N_ - 1);
        const int m1 = min(max(cv.y, 0), N_ - 1);
        const int m2 = min(max(cv.z, 0), N_ - 1);
        const int m3 = min(max(cv.w, 0), N_ - 1);
        const bool p0 = (prevmask[m0 >> 5] >> (m0 & 31)) & 1u;
        const bool p1 = (prevmask[m1 >> 5] >> (m1 & 31)) & 1u;
        const bool p2 = (prevmask[m2 >> 5] >> (m2 & 31)) & 1u;
        const bool p3 = (prevmask[m3 >> 5] >> (m3 & 31)) & 1u;
        vv.x = fminf(fmaxf(vv.x + (p0 ? POT : -PUN), 0.0f), 1.0f);
        vv.y = fminf(fmaxf(vv.y + (p1 ? POT : -PUN), 0.0f), 1.0f);
        vv.z = fminf(fmaxf(vv.z + (p2 ? POT : -PUN), 0.0f), 1.0f);
        vv.w = fminf(fmaxf(vv.w + (p3 ? POT : -PUN), 0.0f), 1.0f);
        *reinterpret_cast<float4*>(vol + base) = vv;

        // patch connected nibble for this (cell, seg, group g)
        const unsigned nib = ((vv.x > PERM_THR || sv.x > PERM_THR) ? 1u : 0u)
                           | ((vv.y > PERM_THR || sv.y > PERM_THR) ? 2u : 0u)
                           | ((vv.z > PERM_THR || sv.z > PERM_THR) ? 4u : 0u)
                           | ((vv.w > PERM_THR || sv.w > PERM_THR) ? 8u : 0u);
        const int chunk = seg >> 1;
        const int slot  = (seg & 1) * 32 + g;                  // lane index in conbits layout
        const unsigned idx = (unsigned)(cellv * 128 + slot * 2 + (chunk >> 3));
        const int shn = 4 * (chunk & 7);
        const unsigned old = conbits32[idx];
        conbits32[idx] = (old & ~(0xFu << shn)) | (nib << shn);  // unique cell per entry: no race
    }
}

// ---------------------------------------------------------------------------
// Kernel 5: phase 2 — conn + conbits only. 4 cells per wave (4 streams),
// peeled pipeline, REVERSED block order so conn's tail (hot in L3 from
// phase1c) is read first. Early exit when no column bursts.
// ---------------------------------------------------------------------------
__global__ __launch_bounds__(256) void phase2c_kernel(const int* __restrict__ conn,
                                                      const unsigned long long* __restrict__ conbits,
                                                      const unsigned* __restrict__ ws,
                                                      float* __restrict__ out_pred_next) {
    __shared__ unsigned nburst_s;
    __shared__ unsigned burstmask[32];
    const int tid = threadIdx.x;
    if (tid == 0) nburst_s = ws[WS_NBURST];
    if (tid >= 64 && tid < 96) burstmask[tid - 64] = ws[WS_BURSTMASK + (tid - 64)];
    __syncthreads();

    const int cbase = ((int)gridDim.x - 1 - (int)blockIdx.x) * 16;   // reversed traversal
    if (nburst_s == 0u) {                       // uniform: no bursting columns
        if (tid < 16) out_pred_next[cbase + tid] = 0.0f;
        return;
    }

    const int wave = tid >> 6;
    const int lane = tid & 63;
    const int half = lane >> 5;
    const int l32  = lane & 31;
    const int sh   = half * 32;

    const int c0i = cbase + wave;               // cells c0i, +4, +8, +12
    const size_t off = (size_t)half * Y_ + (size_t)(l32 * 4);
    const size_t b0 = (size_t)(c0i     ) * (S_ * Y_) + off;
    const size_t b1 = (size_t)(c0i + 4 ) * (S_ * Y_) + off;
    const size_t b2 = (size_t)(c0i + 8 ) * (S_ * Y_) + off;
    const size_t b3 = (size_t)(c0i + 12) * (S_ * Y_) + off;

    unsigned long long q0 = conbits[(size_t)(c0i     ) * 64 + lane];
    unsigned long long q1 = conbits[(size_t)(c0i + 4 ) * 64 + lane];
    unsigned long long q2 = conbits[(size_t)(c0i + 8 ) * 64 + lane];
    unsigned long long q3 = conbits[(size_t)(c0i + 12) * 64 + lane];

    auto proc = [&](const i4 cv, const unsigned nib, bool& predf) {
        const int m0 = min(max(cv[0], 0), N_ - 1) >> 4;   // presyn column id
        const int m1 = min(max(cv[1], 0), N_ - 1) >> 4;
        const int m2 = min(max(cv[2], 0), N_ - 1) >> 4;
        const int m3 = min(max(cv[3], 0), N_ - 1) >> 4;
        const bool p0 = (burstmask[m0 >> 5] >> (m0 & 31)) & 1u;
        const bool p1 = (burstmask[m1 >> 5] >> (m1 & 31)) & 1u;
        const bool p2 = (burstmask[m2 >> 5] >> (m2 & 31)) & 1u;
        const bool p3 = (burstmask[m3 >> 5] >> (m3 & 31)) & 1u;
        const uint64_t ba0 = __ballot(p0 && (nib & 1u)), ba1 = __ballot(p1 && (nib & 2u)),
                       ba2 = __ballot(p2 && (nib & 4u)), ba3 = __ballot(p3 && (nib & 8u));
        const int ac = __popc((unsigned)(ba0 >> sh)) + __popc((unsigned)(ba1 >> sh)) +
                       __popc((unsigned)(ba2 >> sh)) + __popc((unsigned)(ba3 >> sh));
        predf |= (ac >= ACT_THR);
    };

    i4 a0 = *reinterpret_cast<const i4*>(conn + b0);
    i4 a1 = *reinterpret_cast<const i4*>(conn + b1);
    i4 a2 = *reinterpret_cast<const i4*>(conn + b2);
    i4 a3 = *reinterpret_cast<const i4*>(conn + b3);

    bool f0 = false, f1 = false, f2 = false, f3 = false;

    #pragma unroll 3
    for (int i = 0; i < 15; ++i) {
        const size_t d = (size_t)(i + 1) * 256;
        const i4 n0 = *reinterpret_cast<const i4*>(conn + b0 + d);
        const i4 n1 = *reinterpret_cast<const i4*>(conn + b1 + d);
        const i4 n2 = *reinterpret_cast<const i4*>(conn + b2 + d);
        const i4 n3 = *reinterpret_cast<const i4*>(conn + b3 + d);

        proc(a0, (unsigned)q0 & 0xFu, f0); q0 >>= 4;
        proc(a1, (unsigned)q1 & 0xFu, f1); q1 >>= 4;
        proc(a2, (unsigned)q2 & 0xFu, f2); q2 >>= 4;
        proc(a3, (unsigned)q3 & 0xFu, f3); q3 >>= 4;

        a0 = n0; a1 = n1; a2 = n2; a3 = n3;
    }
    proc(a0, (unsigned)q0 & 0xFu, f0);
    proc(a1, (unsigned)q1 & 0xFu, f1);
    proc(a2, (unsigned)q2 & 0xFu, f2);
    proc(a3, (unsigned)q3 & 0xFu, f3);

    const bool g0 = (__any(f0 ? 1 : 0) != 0);
    const bool g1 = (__any(f1 ? 1 : 0) != 0);
    const bool g2 = (__any(f2 ? 1 : 0) != 0);
    const bool g3 = (__any(f3 ? 1 : 0) != 0);
    if (lane == 0) {
        out_pred_next[c0i     ] = g0 ? 1.0f : 0.0f;
        out_pred_next[c0i + 4 ] = g1 ? 1.0f : 0.0f;
        out_pred_next[c0i + 8 ] = g2 ? 1.0f : 0.0f;
        out_pred_next[c0i + 12] = g3 ? 1.0f : 0.0f;
    }
}

// ===========================================================================
// Fallback path (workspace too small for conbits): round-0 verified pipeline.
// ===========================================================================
__global__ __launch_bounds__(256) void phase1_old(const int*   __restrict__ conn,
                                                  const float* __restrict__ vol,
                                                  const float* __restrict__ cons,
                                                  unsigned*    __restrict__ ws) {
    __shared__ unsigned prevmask[512];
    const int tid = threadIdx.x;
    for (int i = tid; i < 512; i += 256) prevmask[i] = ws[WS_PREVMASK + i];
    __syncthreads();

    const int wave = tid >> 6;
    const int lane = tid & 63;
    const int half = lane >> 5;
    const int l32  = lane & 31;
    const int sh   = half * 32;

    #pragma unroll 1
    for (int ci = 0; ci < 2; ++ci) {
        const int cell = blockIdx.x * 8 + wave + ci * 4;
        const size_t cellbase = (size_t)cell * (S_ * Y_) + (size_t)(l32 * 4);

        size_t a = cellbase + (size_t)half * Y_;
        int4   cv_n = *reinterpret_cast<const int4*>(conn + a);
        float4 vv_n = *reinterpret_cast<const float4*>(vol + a);
        float4 sv_n = *reinterpret_cast<const float4*>(cons + a);

        unsigned key = 0u;
        bool predf = false;

        #pragma unroll 2
        for (int i = 0; i < 16; ++i) {
            const int4   cv = cv_n;
            const float4 vv = vv_n;
            const float4 sv = sv_n;
            if (i < 15) {
                const size_t nb = cellbase + (size_t)(2 * (i + 1) + half) * Y_;
                cv_n = *reinterpret_cast<const int4*>(conn + nb);
                vv_n = *reinterpret_cast<const float4*>(vol + nb);
                sv_n = *reinterpret_cast<const float4*>(cons + nb);
            }

            const int m0 = min(max(cv.x, 0), N_ - 1);
            const int m1 = min(max(cv.y, 0), N_ - 1);
            const int m2 = min(max(cv.z, 0), N_ - 1);
            const int m3 = min(max(cv.w, 0), N_ - 1);
            const bool p0 = (prevmask[m0 >> 5] >> (m0 & 31)) & 1u;
            const bool p1 = (prevmask[m1 >> 5] >> (m1 & 31)) & 1u;
            const bool p2 = (prevmask[m2 >> 5] >> (m2 & 31)) & 1u;
            const bool p3 = (prevmask[m3 >> 5] >> (m3 & 31)) & 1u;
            const bool c0 = (vv.x > PERM_THR) || (sv.x > PERM_THR);
            const bool c1 = (vv.y > PERM_THR) || (sv.y > PERM_THR);
            const bool c2 = (vv.z > PERM_THR) || (sv.z > PERM_THR);
            const bool c3 = (vv.w > PERM_THR) || (sv.w > PERM_THR);

            const uint64_t bp0 = __ballot(p0), bp1 = __ballot(p1),
                           bp2 = __ballot(p2), bp3 = __ballot(p3);
            const uint64_t ba0 = __ballot(p0 && c0), ba1 = __ballot(p1 && c1),
                           ba2 = __ballot(p2 && c2), ba3 = __ballot(p3 && c3);

            const int ov = __popc((unsigned)(bp0 >> sh)) + __popc((unsigned)(bp1 >> sh)) +
                           __popc((unsigned)(bp2 >> sh)) + __popc((unsigned)(bp3 >> sh));
            const int ac = __popc((unsigned)(ba0 >> sh)) + __popc((unsigned)(ba1 >> sh)) +
                           __popc((unsigned)(ba2 >> sh)) + __popc((unsigned)(ba3 >> sh));

            predf |= (ac >= ACT_THR);
            const int seg = 2 * i + half;
            const unsigned k2 = ((unsigned)ov << 6) | (unsigned)(63 - seg);
            key = max(key, k2);
        }

        const unsigned okey = (unsigned)__shfl_xor((int)key, 32);
        const unsigned fkey = max(key, okey);
        const bool fpred = (__any(predf ? 1 : 0) != 0);
        if (lane == 0) {
            const int bo = (int)(fkey >> 6);
            const int bs = 63 - (int)(fkey & 63u);
            ws[WS_CELLINFO + cell] = (fpred ? 1u : 0u) | ((unsigned)bs << 8) | ((unsigned)bo << 16);
        }
    }
}

__global__ __launch_bounds__(256) void learn_old(const int* __restrict__ conn,
                                                 float*     __restrict__ vol,
                                                 unsigned*  __restrict__ ws,
                                                 float*     __restrict__ out_acc) {
    __shared__ unsigned prevmask[512];
    const int tid = threadIdx.x;
    for (int i = tid; i < 512; i += 256) prevmask[i] = ws[WS_PREVMASK + i];
    __syncthreads();

    if (blockIdx.x == 0 && tid == 0) {
        const int na  = (int)ws[WS_NUM_ACTIVE];
        const int np_ = (int)ws[WS_NUM_PRED];
        out_acc[0] = (na > 0) ? ((float)np_ / (float)na) : 1.0f;
    }
    if (ws[WS_PREV_ANY] == 0u) return;

    const int cnt    = (int)ws[WS_LEARN_CNT];
    const int wave   = (blockIdx.x * 256 + tid) >> 6;
    const int lane   = tid & 63;
    const int nwaves = gridDim.x * 4;

    for (int e = wave; e < cnt; e += nwaves) {
        const int cell = (int)ws[WS_LIST + e];
        const int seg  = (int)((ws[WS_CELLINFO + cell] >> 8) & 0xFFu);
        const size_t base = ((size_t)cell * S_ + seg) * Y_ + (size_t)(lane * 2);
        const int2 cv = *reinterpret_cast<const int2*>(conn + base);
        float2 vv = *reinterpret_cast<const float2*>(vol + base);
        const int m0 = min(max(cv.x, 0), N_ - 1);
        const int m1 = min(max(cv.y, 0), N_ - 1);
        const bool p0 = (prevmask[m0 >> 5] >> (m0 & 31)) & 1u;
        const bool p1 = (prevmask[m1 >> 5] >> (m1 & 31)) & 1u;
        vv.x = fminf(fmaxf(vv.x + (p0 ? POT : -PUN), 0.0f), 1.0f);
        vv.y = fminf(fmaxf(vv.y + (p1 ? POT : -PUN), 0.0f), 1.0f);
        *reinterpret_cast<float2*>(vol + base) = vv;
    }
}

__global__ __launch_bounds__(256) void phase2_old(const int*   __restrict__ conn,
                                                  const float* __restrict__ vol,
                                                  const float* __restrict__ cons,
                                                  const unsigned* __restrict__ ws,
                                                  float* __restrict__ out_pred_next) {
    __shared__ unsigned nburst_s;
    __shared__ unsigned burstmask[32];
    const int tid = threadIdx.x;
    if (tid == 0) nburst_s = ws[WS_NBURST];
    if (tid >= 64 && tid < 96) burstmask[tid - 64] = ws[WS_BURSTMASK + (tid - 64)];
    __syncthreads();

    const int cbase = blockIdx.x * 8;
    if (nburst_s == 0u) {
        if (tid < 8) out_pred_next[cbase + tid] = 0.0f;
        return;
    }

    const int wave = tid >> 6;
    const int lane = tid & 63;
    const int half = lane >> 5;
    const int l32  = lane & 31;
    const int sh   = half * 32;

    #pragma unroll 1
    for (int ci = 0; ci < 2; ++ci) {
        const int cell = cbase + wave + ci * 4;
        const size_t cellbase = (size_t)cell * (S_ * Y_) + (size_t)(l32 * 4);

        size_t a = cellbase + (size_t)half * Y_;
        int4   cv_n = *reinterpret_cast<const int4*>(conn + a);
        float4 vv_n = *reinterpret_cast<const float4*>(vol + a);
        float4 sv_n = *reinterpret_cast<const float4*>(cons + a);

        bool predf = false;

        #pragma unroll 2
        for (int i = 0; i < 16; ++i) {
            const int4   cv = cv_n;
            const float4 vv = vv_n;
            const float4 sv = sv_n;
            if (i < 15) {
                const size_t nb = cellbase + (size_t)(2 * (i + 1) + half) * Y_;
                cv_n = *reinterpret_cast<const int4*>(conn + nb);
                vv_n = *reinterpret_cast<const float4*>(vol + nb);
                sv_n = *reinterpret_cast<const float4*>(cons + nb);
            }

            const int m0 = min(max(cv.x, 0), N_ - 1) >> 4;
            const int m1 = min(max(cv.y, 0), N_ - 1) >> 4;
            const int m2 = min(max(cv.z, 0), N_ - 1) >> 4;
            const int m3 = min(max(cv.w, 0), N_ - 1) >> 4;
            const bool p0 = (burstmask[m0 >> 5] >> (m0 & 31)) & 1u;
            const bool p1 = (burstmask[m1 >> 5] >> (m1 & 31)) & 1u;
            const bool p2 = (burstmask[m2 >> 5] >> (m2 & 31)) & 1u;
            const bool p3 = (burstmask[m3 >> 5] >> (m3 & 31)) & 1u;
            const bool c0 = (vv.x > PERM_THR) || (sv.x > PERM_THR);
            const bool c1 = (vv.y > PERM_THR) || (sv.y > PERM_THR);
            const bool c2 = (vv.z > PERM_THR) || (sv.z > PERM_THR);
            const bool c3 = (vv.w > PERM_THR) || (sv.w > PERM_THR);

            const uint64_t ba0 = __ballot(p0 && c0), ba1 = __ballot(p1 && c1),
                           ba2 = __ballot(p2 && c2), ba3 = __ballot(p3 && c3);
            const int ac = __popc((unsigned)(ba0 >> sh)) + __popc((unsigned)(ba1 >> sh)) +
                           __popc((unsigned)(ba2 >> sh)) + __popc((unsigned)(ba3 >> sh));
            predf |= (ac >= ACT_THR);
        }

        const bool fpred = (__any(predf ? 1 : 0) != 0);
        if (lane == 0) out_pred_next[cell] = fpred ? 1.0f : 0.0f;
    }
}

// ---------------------------------------------------------------------------
extern "C" void kernel_launch(void* const* d_in, const int* in_sizes, int n_in,
                              void* d_out, int out_size, void* d_ws, size_t ws_size,
                              hipStream_t stream) {
    const int*   x    = (const int*)d_in[0];
    const int*   prev = (const int*)d_in[1];
    const int*   conn = (const int*)d_in[2];
    float*       vol  = (float*)d_in[3];        // updated in place (restored by harness)
    const float* cons = (const float*)d_in[4];
    float*    out = (float*)d_out;              // [0..N): new_active, [N..2N): pred_next, [2N]: acc
    unsigned* ws  = (unsigned*)d_ws;

    const size_t need = (size_t)WS_CONBITS * 4 + (size_t)N_ * 64 * 8;  // 256KB + 8MB

    pack_kernel<<<1, 512, 0, stream>>>(prev, ws);

    if (ws_size >= need) {
        unsigned long long* conbits = (unsigned long long*)(ws + WS_CONBITS);
        phase1c_kernel<<<N_ / 8,  256, 0, stream>>>(conn, vol, cons, conbits, ws);
        column_kernel <<<C_ / 256, 256, 0, stream>>>(x, ws, out);
        learnb_kernel <<<64,      256, 0, stream>>>(conn, vol, cons, ws, out + 2 * N_);
        phase2c_kernel<<<N_ / 16, 256, 0, stream>>>(conn, conbits, ws, out + N_);
    } else {
        phase1_old<<<2048, 256, 0, stream>>>(conn, vol, cons, ws);
        column_kernel<<<C_ / 256, 256, 0, stream>>>(x, ws, out);
        learn_old<<<64, 256, 0, stream>>>(conn, vol, ws, out + 2 * N_);
        phase2_old<<<2048, 256, 0, stream>>>(conn, vol, cons, ws, out + N_);
    }
}